// Round 1
// baseline (1882.868 us; speedup 1.0000x reference)
//
#include <hip/hip_runtime.h>
#include <math.h>

// AFNO2D: out = x + fuse_w @ (x + irfft2(masked_delta))
// where masked_delta = (softshrink(W2*gelu(W1*Z+b1)+b2) - Z) on modes [0:64, 0:33].
// Uses irfft2(rfft2(x)) == x to avoid full FFTs: only the 64x33 masked modes are
// transformed forward and back. All math fp32, ortho norm = 1/128 per direction.
//
// Workspace layout (bytes):
//   zm   @ 0         : B*C*64*33 float2 = 34,603,008   (Z masked modes, then delta in-place)
//   hbuf @ 34603008  : B*C*64*33 float2 = 34,603,008   (MLP hidden; dead after mlp2)
//   yy   @ 34603008  : B*C*128*128 f32  = 134,217,728  (y = x + D; overlays hbuf)
// Peak ws = 168,820,736 bytes.

#define NBLK 8
#define BSZ  64
#define LAMB 0.01f
#define TWO_PI_OVER_128 0.049087385212340517f

static __device__ __forceinline__ float gelu_exact(float v) {
    return 0.5f * v * (1.0f + erff(v * 0.7071067811865475f));
}
static __device__ __forceinline__ float softshrink01(float v) {
    float a = fabsf(v) - LAMB;
    a = a > 0.0f ? a : 0.0f;
    return v >= 0.0f ? a : -a;
}

// ---------------------------------------------------------------------------
// Kernel 1: forward partial rfft2 per (b,c) image.
// Stage 1: DFT along W (128 real -> 33 complex) for all 128 rows (LDS).
// Stage 2: DFT along H (128 -> 64 output rows). Writes zm[bc][r][k], ortho 1/128.
// ---------------------------------------------------------------------------
__global__ __launch_bounds__(256) void k_fwd(const float* __restrict__ x,
                                             float2* __restrict__ zm) {
    __shared__ float xs[16][128];
    __shared__ float zwr[128 * 33];
    __shared__ float zwi[128 * 33];
    __shared__ float twc[128], tws[128];
    const int bc  = blockIdx.x;        // 0..2047  (b*512 + c)
    const int tid = threadIdx.x;

    if (tid < 128) {
        float s, c;
        sincosf((float)tid * TWO_PI_OVER_128, &s, &c);
        twc[tid] = c; tws[tid] = s;
    }

    const float* xim = x + (size_t)bc * 16384;

    // Stage 1: 8 chunks of 16 rows
    for (int chunk = 0; chunk < 8; ++chunk) {
        __syncthreads();  // xs reuse guard (also covers twiddle init on first iter)
        for (int t = tid; t < 2048; t += 256)
            xs[t >> 7][t & 127] = xim[chunk * 2048 + t];
        __syncthreads();
        for (int item = tid; item < 16 * 33; item += 256) {
            int rr = item / 33;
            int k  = item - rr * 33;
            float cr = 0.f, ci = 0.f;
            int idx = 0;
            #pragma unroll 8
            for (int w = 0; w < 128; ++w) {
                float xv = xs[rr][w];
                cr += xv * twc[idx];
                ci -= xv * tws[idx];
                idx = (idx + k) & 127;
            }
            int h = chunk * 16 + rr;
            zwr[h * 33 + k] = cr * 0.0078125f;   // ortho 1/128
            zwi[h * 33 + k] = ci * 0.0078125f;
        }
    }
    __syncthreads();

    // Stage 2: rows 0..63 only
    for (int item = tid; item < 64 * 33; item += 256) {
        int r = item / 33;
        int k = item - r * 33;
        float cr = 0.f, ci = 0.f;
        int idx = 0;
        #pragma unroll 8
        for (int h = 0; h < 128; ++h) {
            float ar = zwr[h * 33 + k], ai = zwi[h * 33 + k];
            float c = twc[idx], s = tws[idx];
            cr += ar * c + ai * s;   // (ar+i*ai)*(c - i*s), real
            ci += ai * c - ar * s;   // imag
            idx = (idx + r) & 127;
        }
        zm[(size_t)bc * 2112 + item] = make_float2(cr, ci);
    }
}

// ---------------------------------------------------------------------------
// Kernel 2a: MLP layer 1 (complex 64x64 per block nb) + exact GELU -> hbuf.
// grid = (33 chunks, 8 nb, 4 b); 256 threads = 4 positions x 64 lanes.
// ---------------------------------------------------------------------------
__global__ __launch_bounds__(256) void k_mlp1(const float* __restrict__ w1r_g,
                                              const float* __restrict__ w1i_g,
                                              const float* __restrict__ b1r_g,
                                              const float* __restrict__ b1i_g,
                                              const float2* __restrict__ zm,
                                              float2* __restrict__ hbuf) {
    __shared__ float w1r[4096], w1i[4096];
    __shared__ float b1r[64], b1i[64];
    __shared__ float zr[4][64], zi[4][64];
    const int chunk = blockIdx.x;   // 0..32
    const int nb    = blockIdx.y;   // 0..7
    const int b     = blockIdx.z;   // 0..3
    const int tid   = threadIdx.x;
    const int lane  = tid & 63;
    const int q     = tid >> 6;

    for (int t = tid; t < 4096; t += 256) {
        w1r[t] = w1r_g[nb * 4096 + t];
        w1i[t] = w1i_g[nb * 4096 + t];
    }
    if (tid < 64) { b1r[tid] = b1r_g[nb * 64 + tid]; b1i[tid] = b1i_g[nb * 64 + tid]; }
    __syncthreads();

    for (int g = 0; g < 16; ++g) {
        int pos = chunk * 64 + g * 4 + q;          // 0..2111
        int r = pos / 33;
        int k = pos - r * 33;
        size_t idx = ((size_t)((b * 512 + nb * 64 + lane) * 64 + r)) * 33 + k;
        float2 z = zm[idx];
        zr[q][lane] = z.x; zi[q][lane] = z.y;
        __syncthreads();
        float yr = b1r[lane], yi = b1i[lane];
        #pragma unroll 16
        for (int i = 0; i < 64; ++i) {
            float ar = zr[q][i], ai = zi[q][i];
            float wr = w1r[i * 64 + lane], wi = w1i[i * 64 + lane];
            yr += ar * wr - ai * wi;
            yi += ar * wi + ai * wr;
        }
        hbuf[idx] = make_float2(gelu_exact(yr), gelu_exact(yi));
        __syncthreads();
    }
}

// ---------------------------------------------------------------------------
// Kernel 2b: MLP layer 2 + softshrink; zm <- delta = softshrink(y2) - z (in place)
// ---------------------------------------------------------------------------
__global__ __launch_bounds__(256) void k_mlp2(const float* __restrict__ w2r_g,
                                              const float* __restrict__ w2i_g,
                                              const float* __restrict__ b2r_g,
                                              const float* __restrict__ b2i_g,
                                              const float2* __restrict__ hbuf,
                                              float2* __restrict__ zm) {
    __shared__ float w2r[4096], w2i[4096];
    __shared__ float b2r[64], b2i[64];
    __shared__ float hr[4][64], hi[4][64];
    const int chunk = blockIdx.x;
    const int nb    = blockIdx.y;
    const int b     = blockIdx.z;
    const int tid   = threadIdx.x;
    const int lane  = tid & 63;
    const int q     = tid >> 6;

    for (int t = tid; t < 4096; t += 256) {
        w2r[t] = w2r_g[nb * 4096 + t];
        w2i[t] = w2i_g[nb * 4096 + t];
    }
    if (tid < 64) { b2r[tid] = b2r_g[nb * 64 + tid]; b2i[tid] = b2i_g[nb * 64 + tid]; }
    __syncthreads();

    for (int g = 0; g < 16; ++g) {
        int pos = chunk * 64 + g * 4 + q;
        int r = pos / 33;
        int k = pos - r * 33;
        size_t idx = ((size_t)((b * 512 + nb * 64 + lane) * 64 + r)) * 33 + k;
        float2 h = hbuf[idx];
        hr[q][lane] = h.x; hi[q][lane] = h.y;
        __syncthreads();
        float yr = b2r[lane], yi = b2i[lane];
        #pragma unroll 16
        for (int i = 0; i < 64; ++i) {
            float ar = hr[q][i], ai = hi[q][i];
            float wr = w2r[i * 64 + lane], wi = w2i[i * 64 + lane];
            yr += ar * wr - ai * wi;
            yi += ar * wi + ai * wr;
        }
        float2 z = zm[idx];
        zm[idx] = make_float2(softshrink01(yr) - z.x, softshrink01(yi) - z.y);
        __syncthreads();
    }
}

// ---------------------------------------------------------------------------
// Kernel 3: inverse per (b,c): iDFT along H (64 -> 128 rows), then c2r along W
// (33 -> 128, Hermitian doubling, DC imag dropped per numpy irfft), scale 1/128,
// writes yy = x + D.
// ---------------------------------------------------------------------------
__global__ __launch_bounds__(256) void k_inv(const float2* __restrict__ zm,
                                             const float* __restrict__ x,
                                             float* __restrict__ yy) {
    __shared__ float dr[64 * 33], di[64 * 33];
    __shared__ float Tr[128 * 33], Ti[128 * 33];
    __shared__ float twc[128], tws[128];
    const int bc  = blockIdx.x;
    const int tid = threadIdx.x;

    if (tid < 128) {
        float s, c;
        sincosf((float)tid * TWO_PI_OVER_128, &s, &c);
        twc[tid] = c; tws[tid] = s;
    }
    for (int t = tid; t < 2112; t += 256) {
        float2 v = zm[(size_t)bc * 2112 + t];
        dr[t] = v.x; di[t] = v.y;
    }
    __syncthreads();

    // Stage 1: T[h][k] = sum_r d[r][k] * e^{+2πi r h/128}
    for (int item = tid; item < 128 * 33; item += 256) {
        int h = item / 33;
        int k = item - h * 33;
        float cr = 0.f, ci = 0.f;
        int idx = 0;
        #pragma unroll 8
        for (int r = 0; r < 64; ++r) {
            float ar = dr[r * 33 + k], ai = di[r * 33 + k];
            float c = twc[idx], s = tws[idx];
            cr += ar * c - ai * s;
            ci += ai * c + ar * s;
            idx = (idx + h) & 127;
        }
        Tr[item] = cr; Ti[item] = ci;
    }
    __syncthreads();

    // Stage 2: c2r along W. D[h][w] = (Tr[h][0] + 2*sum_{k=1..32} Re(T e^{+2πikw/128}))/128
    const size_t base = (size_t)bc * 16384;
    for (int item = tid; item < 16384; item += 256) {
        int h = item >> 7;
        int w = item & 127;
        float v = Tr[h * 33];       // k=0: DC imag dropped (numpy irfft semantics)
        float acc = 0.f;
        int kw = 0;
        #pragma unroll 8
        for (int k = 1; k <= 32; ++k) {
            kw = (kw + w) & 127;
            acc += Tr[h * 33 + k] * twc[kw] - Ti[h * 33 + k] * tws[kw];
        }
        v += 2.0f * acc;
        yy[base + item] = x[base + item] + v * 0.0078125f;  // ortho 1/128
    }
}

// ---------------------------------------------------------------------------
// Kernel 4: out[b][o][p] = x[b][o][p] + sum_c fw[o][c] * yy[b][c][p]
// 128x128 output tile, K-chunks of 8, 8x8 micro-tile per thread.
// ---------------------------------------------------------------------------
__global__ __launch_bounds__(256) void k_conv(const float* __restrict__ x,
                                              const float* __restrict__ yy,
                                              const float* __restrict__ fw,
                                              float* __restrict__ out) {
    __shared__ float As[8][128];   // [k][o]
    __shared__ float Bs[8][128];   // [k][p]
    const int pt  = blockIdx.x;    // 0..127
    const int ot  = blockIdx.y;    // 0..3
    const int b   = blockIdx.z;    // 0..3
    const int tid = threadIdx.x;
    const int tx  = tid & 15, ty = tid >> 4;
    const int p0  = pt * 128, o0 = ot * 128;

    float acc[8][8] = {};

    for (int kc = 0; kc < 512; kc += 8) {
        // A tile: fw[o0+oo][kc+kk] -> As[kk][oo]
        {
            int oo  = tid >> 1;
            int kk0 = (tid & 1) * 4;
            float4 a = *(const float4*)&fw[(size_t)(o0 + oo) * 512 + kc + kk0];
            As[kk0 + 0][oo] = a.x; As[kk0 + 1][oo] = a.y;
            As[kk0 + 2][oo] = a.z; As[kk0 + 3][oo] = a.w;
        }
        // B tile: yy[(b*512+kc+kk)][p0 + pp], vectorized
        {
            int kk = tid >> 5;
            int f4 = tid & 31;
            float4 v = *(const float4*)&yy[(((size_t)(b * 512 + kc + kk)) << 14) + p0 + f4 * 4];
            *(float4*)&Bs[kk][f4 * 4] = v;
        }
        __syncthreads();
        #pragma unroll
        for (int kk = 0; kk < 8; ++kk) {
            float av[8], bv[8];
            #pragma unroll
            for (int i = 0; i < 8; ++i) av[i] = As[kk][ty * 8 + i];
            #pragma unroll
            for (int j = 0; j < 8; ++j) bv[j] = Bs[kk][tx * 8 + j];
            #pragma unroll
            for (int i = 0; i < 8; ++i)
                #pragma unroll
                for (int j = 0; j < 8; ++j)
                    acc[i][j] += av[i] * bv[j];
        }
        __syncthreads();
    }

    #pragma unroll
    for (int i = 0; i < 8; ++i) {
        int o = o0 + ty * 8 + i;
        size_t base = (((size_t)(b * 512 + o)) << 14) + p0 + tx * 8;
        float4 x0 = *(const float4*)&x[base];
        float4 x1 = *(const float4*)&x[base + 4];
        float4 r0 = make_float4(x0.x + acc[i][0], x0.y + acc[i][1], x0.z + acc[i][2], x0.w + acc[i][3]);
        float4 r1 = make_float4(x1.x + acc[i][4], x1.y + acc[i][5], x1.z + acc[i][6], x1.w + acc[i][7]);
        *(float4*)&out[base]     = r0;
        *(float4*)&out[base + 4] = r1;
    }
}

// ---------------------------------------------------------------------------
extern "C" void kernel_launch(void* const* d_in, const int* in_sizes, int n_in,
                              void* d_out, int out_size, void* d_ws, size_t ws_size,
                              hipStream_t stream) {
    const float* x   = (const float*)d_in[0];
    const float* w1r = (const float*)d_in[1];
    const float* w1i = (const float*)d_in[2];
    const float* b1r = (const float*)d_in[3];
    const float* b1i = (const float*)d_in[4];
    const float* w2r = (const float*)d_in[5];
    const float* w2i = (const float*)d_in[6];
    const float* b2r = (const float*)d_in[7];
    const float* b2i = (const float*)d_in[8];
    const float* fw  = (const float*)d_in[9];
    float* out = (float*)d_out;

    char* ws = (char*)d_ws;
    float2* zm   = (float2*)ws;                          // 34,603,008 B
    float2* hbuf = (float2*)(ws + 34603008);             // 34,603,008 B (dead after mlp2)
    float*  yy   = (float*)(ws + 34603008);              // 134,217,728 B (overlays hbuf)

    k_fwd<<<2048, 256, 0, stream>>>(x, zm);
    k_mlp1<<<dim3(33, 8, 4), 256, 0, stream>>>(w1r, w1i, b1r, b1i, zm, hbuf);
    k_mlp2<<<dim3(33, 8, 4), 256, 0, stream>>>(w2r, w2i, b2r, b2i, hbuf, zm);
    k_inv<<<2048, 256, 0, stream>>>(zm, x, yy);
    k_conv<<<dim3(128, 4, 4), 256, 0, stream>>>(x, yy, fw, out);
}

// Round 2
// 1438.752 us; speedup vs baseline: 1.3087x; 1.3087x over previous
//
#include <hip/hip_runtime.h>
#include <math.h>

// AFNO2D: out = x + fuse_w @ (x + irfft2(masked_delta))
// masked_delta = (softshrink(W2*gelu(W1*Z+b1)+b2) - Z) on modes [0:64, 0:33] of
// the (128 x 65) rfft2 spectrum. Uses irfft2(rfft2(x)) == x so only the 64x33
// masked modes are transformed. All twiddles via per-thread rotation recurrence
// (registers) -> no LDS twiddle tables, no bank conflicts. fp32 throughout.
//
// Workspace layout (bytes):
//   zm   @ 0         : B*C*64*33 float2 = 34,603,008   (Z modes, then delta in place)
//   hbuf @ 34603008  : B*C*64*33 float2 = 34,603,008   (MLP hidden; dead after mlp2)
//   yy   @ 34603008  : B*C*128*128 f32  = 134,217,728  (y = x + D; overlays hbuf)
//   zwg  @ 69206016  : B*C*128*33 float2 = 69,206,016  (W-DFT intermediate; dead
//                      after k_fwd2, overlaps yy region only temporally-disjoint)
// Peak ws = 168,820,736 bytes.

#define LAMB 0.01f
#define TWO_PI_OVER_128 0.049087385212340517f

static __device__ __forceinline__ float gelu_exact(float v) {
    return 0.5f * v * (1.0f + erff(v * 0.7071067811865475f));
}
static __device__ __forceinline__ float softshrink01(float v) {
    float a = fabsf(v) - LAMB;
    a = a > 0.0f ? a : 0.0f;
    return v >= 0.0f ? a : -a;
}

// ---------------------------------------------------------------------------
// Kernel 1a: W-axis DFT (128 real -> 33 complex), ortho scale 1/128 applied.
// grid (2048 images, 2 row-halves), 256 threads = 16 rowgroups(x4 rows) x 16 kg.
// Thread: rows rg*4..+3, k in {kg, kg+16, (32 if kg==0)}; rotation in registers.
// LDS reads: xs broadcast/2-way only. Writes zwg[bc][h][k].
// ---------------------------------------------------------------------------
__global__ __launch_bounds__(256) void k_fwd1(const float* __restrict__ x,
                                              float2* __restrict__ zwg) {
    __shared__ float xs[64][132];   // 33.8 KB; row stride 132 (16B-aligned, bank-safe)
    const int bc   = blockIdx.x;
    const int half = blockIdx.y;
    const int tid  = threadIdx.x;
    const int rg = tid >> 4;        // 0..15
    const int kg = tid & 15;        // 0..15

    const float* xim = x + (size_t)bc * 16384 + half * 8192;
    for (int i = tid; i < 2048; i += 256) {
        int row = i >> 5, f4 = i & 31;
        *(float4*)&xs[row][f4 * 4] = *(const float4*)&xim[row * 128 + f4 * 4];
    }
    __syncthreads();

    float2* zrow = zwg + (size_t)bc * 4224 + half * (64 * 33);
    for (int t = 0; t < 3; ++t) {
        if (t == 2 && kg != 0) break;
        const int k = (t < 2) ? (kg + 16 * t) : 32;
        float sc, ss;
        sincosf((float)k * TWO_PI_OVER_128, &ss, &sc);
        float c = 1.0f, s = 0.0f;
        float cr[4] = {0.f, 0.f, 0.f, 0.f}, ci[4] = {0.f, 0.f, 0.f, 0.f};
        for (int w = 0; w < 128; ++w) {
            float xv0 = xs[rg * 4 + 0][w];
            float xv1 = xs[rg * 4 + 1][w];
            float xv2 = xs[rg * 4 + 2][w];
            float xv3 = xs[rg * 4 + 3][w];
            cr[0] += xv0 * c; ci[0] -= xv0 * s;
            cr[1] += xv1 * c; ci[1] -= xv1 * s;
            cr[2] += xv2 * c; ci[2] -= xv2 * s;
            cr[3] += xv3 * c; ci[3] -= xv3 * s;
            float cn = c * sc - s * ss;
            s = s * sc + c * ss;
            c = cn;
        }
        #pragma unroll
        for (int i = 0; i < 4; ++i)
            zrow[(rg * 4 + i) * 33 + k] =
                make_float2(cr[i] * 0.0078125f, ci[i] * 0.0078125f);
    }
}

// ---------------------------------------------------------------------------
// Kernel 1b: H-axis DFT (128 -> 64 rows) on the 33 k-columns. grid 2048.
// 256 threads = 64 r x 4 kq; thread: k = kq*8..+7 (+ k=32 for kq==0).
// LDS: zw[128][34] float2 (padded for b128). Rotation step r in registers.
// Writes zm[bc][r*33+k].
// ---------------------------------------------------------------------------
__global__ __launch_bounds__(256) void k_fwd2(const float2* __restrict__ zwg,
                                              float2* __restrict__ zm) {
    __shared__ float2 zw[128][34];   // 34.8 KB
    const int bc  = blockIdx.x;
    const int tid = threadIdx.x;

    const float2* src = zwg + (size_t)bc * 4224;
    for (int t = tid; t < 4224; t += 256) {
        int h = t / 33;
        int k = t - h * 33;
        zw[h][k] = src[t];
    }
    __syncthreads();

    const int r  = tid >> 2;   // 0..63
    const int kq = tid & 3;    // 0..3
    float sc, ss;
    sincosf((float)r * TWO_PI_OVER_128, &ss, &sc);
    float c = 1.0f, s = 0.0f;
    float ar[8] = {}, ai[8] = {};
    float tr = 0.f, tiv = 0.f;

    for (int h = 0; h < 128; ++h) {
        const float4* rowp = (const float4*)&zw[h][kq * 8];
        float4 v0 = rowp[0], v1 = rowp[1], v2 = rowp[2], v3 = rowp[3];
        // e^{-i theta}: re += x*c + y*s ; im += y*c - x*s
        ar[0] += v0.x * c + v0.y * s;  ai[0] += v0.y * c - v0.x * s;
        ar[1] += v0.z * c + v0.w * s;  ai[1] += v0.w * c - v0.z * s;
        ar[2] += v1.x * c + v1.y * s;  ai[2] += v1.y * c - v1.x * s;
        ar[3] += v1.z * c + v1.w * s;  ai[3] += v1.w * c - v1.z * s;
        ar[4] += v2.x * c + v2.y * s;  ai[4] += v2.y * c - v2.x * s;
        ar[5] += v2.z * c + v2.w * s;  ai[5] += v2.w * c - v2.z * s;
        ar[6] += v3.x * c + v3.y * s;  ai[6] += v3.y * c - v3.x * s;
        ar[7] += v3.z * c + v3.w * s;  ai[7] += v3.w * c - v3.z * s;
        if (kq == 0) {
            float2 v = zw[h][32];
            tr  += v.x * c + v.y * s;
            tiv += v.y * c - v.x * s;
        }
        float cn = c * sc - s * ss;
        s = s * sc + c * ss;
        c = cn;
    }

    float2* zrow = zm + (size_t)bc * 2112 + r * 33;
    #pragma unroll
    for (int j = 0; j < 8; ++j) zrow[kq * 8 + j] = make_float2(ar[j], ai[j]);
    if (kq == 0) zrow[32] = make_float2(tr, tiv);
}

// ---------------------------------------------------------------------------
// Kernel 2a: MLP layer 1 (complex 64x64 per block nb) + exact GELU -> hbuf.
// ---------------------------------------------------------------------------
__global__ __launch_bounds__(256) void k_mlp1(const float* __restrict__ w1r_g,
                                              const float* __restrict__ w1i_g,
                                              const float* __restrict__ b1r_g,
                                              const float* __restrict__ b1i_g,
                                              const float2* __restrict__ zm,
                                              float2* __restrict__ hbuf) {
    __shared__ float w1r[4096], w1i[4096];
    __shared__ float b1r[64], b1i[64];
    __shared__ float zr[4][64], zi[4][64];
    const int chunk = blockIdx.x;   // 0..32
    const int nb    = blockIdx.y;   // 0..7
    const int b     = blockIdx.z;   // 0..3
    const int tid   = threadIdx.x;
    const int lane  = tid & 63;
    const int q     = tid >> 6;

    for (int t = tid; t < 4096; t += 256) {
        w1r[t] = w1r_g[nb * 4096 + t];
        w1i[t] = w1i_g[nb * 4096 + t];
    }
    if (tid < 64) { b1r[tid] = b1r_g[nb * 64 + tid]; b1i[tid] = b1i_g[nb * 64 + tid]; }
    __syncthreads();

    for (int g = 0; g < 16; ++g) {
        int pos = chunk * 64 + g * 4 + q;          // 0..2111
        int r = pos / 33;
        int k = pos - r * 33;
        size_t idx = ((size_t)((b * 512 + nb * 64 + lane) * 64 + r)) * 33 + k;
        float2 z = zm[idx];
        zr[q][lane] = z.x; zi[q][lane] = z.y;
        __syncthreads();
        float yr = b1r[lane], yi = b1i[lane];
        #pragma unroll 16
        for (int i = 0; i < 64; ++i) {
            float arv = zr[q][i], aiv = zi[q][i];
            float wr = w1r[i * 64 + lane], wi = w1i[i * 64 + lane];
            yr += arv * wr - aiv * wi;
            yi += arv * wi + aiv * wr;
        }
        hbuf[idx] = make_float2(gelu_exact(yr), gelu_exact(yi));
        __syncthreads();
    }
}

// ---------------------------------------------------------------------------
// Kernel 2b: MLP layer 2 + softshrink; zm <- delta = softshrink(y2) - z
// ---------------------------------------------------------------------------
__global__ __launch_bounds__(256) void k_mlp2(const float* __restrict__ w2r_g,
                                              const float* __restrict__ w2i_g,
                                              const float* __restrict__ b2r_g,
                                              const float* __restrict__ b2i_g,
                                              const float2* __restrict__ hbuf,
                                              float2* __restrict__ zm) {
    __shared__ float w2r[4096], w2i[4096];
    __shared__ float b2r[64], b2i[64];
    __shared__ float hr[4][64], hi[4][64];
    const int chunk = blockIdx.x;
    const int nb    = blockIdx.y;
    const int b     = blockIdx.z;
    const int tid   = threadIdx.x;
    const int lane  = tid & 63;
    const int q     = tid >> 6;

    for (int t = tid; t < 4096; t += 256) {
        w2r[t] = w2r_g[nb * 4096 + t];
        w2i[t] = w2i_g[nb * 4096 + t];
    }
    if (tid < 64) { b2r[tid] = b2r_g[nb * 64 + tid]; b2i[tid] = b2i_g[nb * 64 + tid]; }
    __syncthreads();

    for (int g = 0; g < 16; ++g) {
        int pos = chunk * 64 + g * 4 + q;
        int r = pos / 33;
        int k = pos - r * 33;
        size_t idx = ((size_t)((b * 512 + nb * 64 + lane) * 64 + r)) * 33 + k;
        float2 h = hbuf[idx];
        hr[q][lane] = h.x; hi[q][lane] = h.y;
        __syncthreads();
        float yr = b2r[lane], yi = b2i[lane];
        #pragma unroll 16
        for (int i = 0; i < 64; ++i) {
            float arv = hr[q][i], aiv = hi[q][i];
            float wr = w2r[i * 64 + lane], wi = w2i[i * 64 + lane];
            yr += arv * wr - aiv * wi;
            yi += arv * wi + aiv * wr;
        }
        float2 z = zm[idx];
        zm[idx] = make_float2(softshrink01(yr) - z.x, softshrink01(yi) - z.y);
        __syncthreads();
    }
}

// ---------------------------------------------------------------------------
// Kernel 3: inverse per (b,c). Stage 1: iDFT along H (64 delta rows -> 128 rows,
// e^{+i}), rotation step h. Stage 2: c2r along W via paired-k float4 LDS reads
// (T stored at slot k+1 in rows padded to 34 so pairs (odd,even) are 16B-aligned),
// rotation step w. yy = x + D, ortho 1/128 (DC folded 0.5, all k>=1 doubled --
// k=32 is an interior bin of the 65-wide rfft, so it IS doubled w/ imag).
// ---------------------------------------------------------------------------
__global__ __launch_bounds__(256) void k_inv(const float2* __restrict__ zm,
                                             const float* __restrict__ x,
                                             float* __restrict__ yy) {
    __shared__ float2 dbuf[64][33];   // 16.9 KB, flat-copied
    __shared__ float2 Tbuf[128][34];  // 34.8 KB, slot = k+1 (slot 0 unused)
    const int bc  = blockIdx.x;
    const int tid = threadIdx.x;

    for (int t = tid; t < 2112; t += 256)
        ((float2*)dbuf)[t] = zm[(size_t)bc * 2112 + t];
    __syncthreads();

    // Stage 1: T[h][k] = sum_r d[r][k] * e^{+2pi i r h/128}
    {
        const int h  = tid & 127;
        const int kg = tid >> 7;         // 0: even k (17 of them), 1: odd k (16)
        float sc, ss;
        sincosf((float)h * TWO_PI_OVER_128, &ss, &sc);
        float c = 1.0f, s = 0.0f;
        float ar[17], ai[17];
        #pragma unroll
        for (int j = 0; j < 17; ++j) { ar[j] = 0.f; ai[j] = 0.f; }
        for (int r = 0; r < 64; ++r) {
            #pragma unroll
            for (int j = 0; j < 17; ++j) {
                const int k = kg + 2 * j;
                if (k <= 32) {           // only kg==1, j==16 fails (uniform)
                    float2 v = dbuf[r][k];
                    ar[j] += v.x * c - v.y * s;
                    ai[j] += v.y * c + v.x * s;
                }
            }
            float cn = c * sc - s * ss;
            s = s * sc + c * ss;
            c = cn;
        }
        #pragma unroll
        for (int j = 0; j < 17; ++j) {
            const int k = kg + 2 * j;
            if (k <= 32) Tbuf[h][k + 1] = make_float2(ar[j], ai[j]);
        }
    }
    __syncthreads();

    // Stage 2: D[h][w] = (Tr[h][0] + 2*sum_{k=1..32} Re(T[h][k] e^{+2pi i k w/128}))/128
    {
        const int w    = tid & 127;
        const int half = tid >> 7;
        float sc, ss;
        sincosf((float)w * TWO_PI_OVER_128, &ss, &sc);
        const size_t base = (size_t)bc * 16384;
        for (int hg = 0; hg < 8; ++hg) {
            const int h0 = half * 64 + hg * 8;
            float acc[8];
            #pragma unroll
            for (int i = 0; i < 8; ++i) acc[i] = 0.5f * Tbuf[h0 + i][1].x;  // DC
            float c = sc, s = ss;   // rotation at k=1
            #pragma unroll
            for (int p = 0; p < 16; ++p) {          // k pair (1+2p, 2+2p)
                float c1 = c * sc - s * ss;
                float s1 = s * sc + c * ss;
                #pragma unroll
                for (int i = 0; i < 8; ++i) {
                    float4 v = *(const float4*)&Tbuf[h0 + i][2 + 2 * p];
                    acc[i] += v.x * c - v.y * s + v.z * c1 - v.w * s1;
                }
                c = c1 * sc - s1 * ss;
                s = s1 * sc + c1 * ss;
            }
            #pragma unroll
            for (int i = 0; i < 8; ++i) {
                size_t idx = base + (size_t)(h0 + i) * 128 + w;
                yy[idx] = x[idx] + acc[i] * 0.015625f;   // 2/128
            }
        }
    }
}

// ---------------------------------------------------------------------------
// Kernel 4: out[b][o][p] = x[b][o][p] + sum_c fw[o][c] * yy[b][c][p]
// ---------------------------------------------------------------------------
__global__ __launch_bounds__(256) void k_conv(const float* __restrict__ x,
                                              const float* __restrict__ yy,
                                              const float* __restrict__ fw,
                                              float* __restrict__ out) {
    __shared__ float As[8][128];   // [k][o]
    __shared__ float Bs[8][128];   // [k][p]
    const int pt  = blockIdx.x;    // 0..127
    const int ot  = blockIdx.y;    // 0..3
    const int b   = blockIdx.z;    // 0..3
    const int tid = threadIdx.x;
    const int tx  = tid & 15, ty = tid >> 4;
    const int p0  = pt * 128, o0 = ot * 128;

    float acc[8][8] = {};

    for (int kc = 0; kc < 512; kc += 8) {
        {
            int oo  = tid >> 1;
            int kk0 = (tid & 1) * 4;
            float4 a = *(const float4*)&fw[(size_t)(o0 + oo) * 512 + kc + kk0];
            As[kk0 + 0][oo] = a.x; As[kk0 + 1][oo] = a.y;
            As[kk0 + 2][oo] = a.z; As[kk0 + 3][oo] = a.w;
        }
        {
            int kk = tid >> 5;
            int f4 = tid & 31;
            float4 v = *(const float4*)&yy[(((size_t)(b * 512 + kc + kk)) << 14) + p0 + f4 * 4];
            *(float4*)&Bs[kk][f4 * 4] = v;
        }
        __syncthreads();
        #pragma unroll
        for (int kk = 0; kk < 8; ++kk) {
            float av[8], bv[8];
            #pragma unroll
            for (int i = 0; i < 8; ++i) av[i] = As[kk][ty * 8 + i];
            #pragma unroll
            for (int j = 0; j < 8; ++j) bv[j] = Bs[kk][tx * 8 + j];
            #pragma unroll
            for (int i = 0; i < 8; ++i)
                #pragma unroll
                for (int j = 0; j < 8; ++j)
                    acc[i][j] += av[i] * bv[j];
        }
        __syncthreads();
    }

    #pragma unroll
    for (int i = 0; i < 8; ++i) {
        int o = o0 + ty * 8 + i;
        size_t base = (((size_t)(b * 512 + o)) << 14) + p0 + tx * 8;
        float4 x0 = *(const float4*)&x[base];
        float4 x1 = *(const float4*)&x[base + 4];
        float4 r0 = make_float4(x0.x + acc[i][0], x0.y + acc[i][1], x0.z + acc[i][2], x0.w + acc[i][3]);
        float4 r1 = make_float4(x1.x + acc[i][4], x1.y + acc[i][5], x1.z + acc[i][6], x1.w + acc[i][7]);
        *(float4*)&out[base]     = r0;
        *(float4*)&out[base + 4] = r1;
    }
}

// ---------------------------------------------------------------------------
extern "C" void kernel_launch(void* const* d_in, const int* in_sizes, int n_in,
                              void* d_out, int out_size, void* d_ws, size_t ws_size,
                              hipStream_t stream) {
    const float* x   = (const float*)d_in[0];
    const float* w1r = (const float*)d_in[1];
    const float* w1i = (const float*)d_in[2];
    const float* b1r = (const float*)d_in[3];
    const float* b1i = (const float*)d_in[4];
    const float* w2r = (const float*)d_in[5];
    const float* w2i = (const float*)d_in[6];
    const float* b2r = (const float*)d_in[7];
    const float* b2i = (const float*)d_in[8];
    const float* fw  = (const float*)d_in[9];
    float* out = (float*)d_out;

    char* ws = (char*)d_ws;
    float2* zm   = (float2*)ws;                          // 34,603,008 B
    float2* hbuf = (float2*)(ws + 34603008);             // 34,603,008 B
    float*  yy   = (float*)(ws + 34603008);              // 134,217,728 B (overlays hbuf)
    float2* zwg  = (float2*)(ws + 69206016);             // 69,206,016 B (dead after fwd2)

    k_fwd1<<<dim3(2048, 2), 256, 0, stream>>>(x, zwg);
    k_fwd2<<<2048, 256, 0, stream>>>(zwg, zm);
    k_mlp1<<<dim3(33, 8, 4), 256, 0, stream>>>(w1r, w1i, b1r, b1i, zm, hbuf);
    k_mlp2<<<dim3(33, 8, 4), 256, 0, stream>>>(w2r, w2i, b2r, b2i, hbuf, zm);
    k_inv<<<2048, 256, 0, stream>>>(zm, x, yy);
    k_conv<<<dim3(128, 4, 4), 256, 0, stream>>>(x, yy, fw, out);
}

// Round 3
// 1166.370 us; speedup vs baseline: 1.6143x; 1.2335x over previous
//
#include <hip/hip_runtime.h>
#include <math.h>

// AFNO2D: out = x + fuse_w @ (x + irfft2(masked_delta))
// masked_delta = (softshrink(W2*gelu(W1*Z+b1)+b2) - Z) on modes [0:64, 0:33].
// Only the 64x33 masked modes are transformed (irfft2(rfft2(x)) == x).
// DFTs: per-thread twiddle rotation in registers. Conv: bf16 MFMA GEMM.
//
// Workspace layout (bytes), peak 168,820,736:
//   zm    @ 0          : B*C*64*33 float2  = 34,603,008  (Z modes, then delta)
//   hbuf  @ 34,603,008 : B*C*64*33 float2  = 34,603,008  (MLP hidden; dead after mlp2)
//   zwg   @ 34,603,008 : B*C*128*33 float2 = 69,206,016  (dead after fwd2; temporal overlap ok)
//   yy_bf @ 34,603,008 : B*C*128*128 bf16  = 67,108,864  (y = x + D, bf16; dead after k_tr)
//   yy_t  @101,711,872 : B*16384*512 bf16  = 67,108,864  (y transposed [b][p][c])
//   fw_bf @ 34,603,008 : 512*512 bf16      = 524,288     (written after k_tr; yy_bf dead)

#define LAMB 0.01f
#define TWO_PI_OVER_128 0.049087385212340517f

typedef __attribute__((ext_vector_type(8))) short s8bf;           // 8 bf16 (4 VGPRs)
typedef __attribute__((ext_vector_type(8))) unsigned short us8;
typedef __attribute__((ext_vector_type(4))) float f32x4;

static __device__ __forceinline__ float gelu_exact(float v) {
    return 0.5f * v * (1.0f + erff(v * 0.7071067811865475f));
}
static __device__ __forceinline__ float softshrink01(float v) {
    float a = fabsf(v) - LAMB;
    a = a > 0.0f ? a : 0.0f;
    return v >= 0.0f ? a : -a;
}
static __device__ __forceinline__ unsigned short f2bf(float f) {
    union { float f; unsigned int u; } v; v.f = f;
    unsigned int r = v.u + 0x7FFFu + ((v.u >> 16) & 1u);   // RNE
    return (unsigned short)(r >> 16);
}

// ---------------------------------------------------------------------------
// Kernel 1a: W-axis DFT (128 real -> 33 complex), ortho 1/128.
// ---------------------------------------------------------------------------
__global__ __launch_bounds__(256) void k_fwd1(const float* __restrict__ x,
                                              float2* __restrict__ zwg) {
    __shared__ float xs[64][132];
    const int bc   = blockIdx.x;
    const int half = blockIdx.y;
    const int tid  = threadIdx.x;
    const int rg = tid >> 4;
    const int kg = tid & 15;

    const float* xim = x + (size_t)bc * 16384 + half * 8192;
    for (int i = tid; i < 2048; i += 256) {
        int row = i >> 5, f4 = i & 31;
        *(float4*)&xs[row][f4 * 4] = *(const float4*)&xim[row * 128 + f4 * 4];
    }
    __syncthreads();

    float2* zrow = zwg + (size_t)bc * 4224 + half * (64 * 33);
    for (int t = 0; t < 3; ++t) {
        if (t == 2 && kg != 0) break;
        const int k = (t < 2) ? (kg + 16 * t) : 32;
        float sc, ss;
        sincosf((float)k * TWO_PI_OVER_128, &ss, &sc);
        float c = 1.0f, s = 0.0f;
        float cr[4] = {0.f, 0.f, 0.f, 0.f}, ci[4] = {0.f, 0.f, 0.f, 0.f};
        for (int w = 0; w < 128; ++w) {
            float xv0 = xs[rg * 4 + 0][w];
            float xv1 = xs[rg * 4 + 1][w];
            float xv2 = xs[rg * 4 + 2][w];
            float xv3 = xs[rg * 4 + 3][w];
            cr[0] += xv0 * c; ci[0] -= xv0 * s;
            cr[1] += xv1 * c; ci[1] -= xv1 * s;
            cr[2] += xv2 * c; ci[2] -= xv2 * s;
            cr[3] += xv3 * c; ci[3] -= xv3 * s;
            float cn = c * sc - s * ss;
            s = s * sc + c * ss;
            c = cn;
        }
        #pragma unroll
        for (int i = 0; i < 4; ++i)
            zrow[(rg * 4 + i) * 33 + k] =
                make_float2(cr[i] * 0.0078125f, ci[i] * 0.0078125f);
    }
}

// ---------------------------------------------------------------------------
// Kernel 1b: H-axis DFT (128 -> 64 rows) on 33 k-columns.
// ---------------------------------------------------------------------------
__global__ __launch_bounds__(256) void k_fwd2(const float2* __restrict__ zwg,
                                              float2* __restrict__ zm) {
    __shared__ float2 zw[128][34];
    const int bc  = blockIdx.x;
    const int tid = threadIdx.x;

    const float2* src = zwg + (size_t)bc * 4224;
    for (int t = tid; t < 4224; t += 256) {
        int h = t / 33;
        int k = t - h * 33;
        zw[h][k] = src[t];
    }
    __syncthreads();

    const int r  = tid >> 2;
    const int kq = tid & 3;
    float sc, ss;
    sincosf((float)r * TWO_PI_OVER_128, &ss, &sc);
    float c = 1.0f, s = 0.0f;
    float ar[8] = {}, ai[8] = {};
    float tr = 0.f, tiv = 0.f;

    for (int h = 0; h < 128; ++h) {
        const float4* rowp = (const float4*)&zw[h][kq * 8];
        float4 v0 = rowp[0], v1 = rowp[1], v2 = rowp[2], v3 = rowp[3];
        ar[0] += v0.x * c + v0.y * s;  ai[0] += v0.y * c - v0.x * s;
        ar[1] += v0.z * c + v0.w * s;  ai[1] += v0.w * c - v0.z * s;
        ar[2] += v1.x * c + v1.y * s;  ai[2] += v1.y * c - v1.x * s;
        ar[3] += v1.z * c + v1.w * s;  ai[3] += v1.w * c - v1.z * s;
        ar[4] += v2.x * c + v2.y * s;  ai[4] += v2.y * c - v2.x * s;
        ar[5] += v2.z * c + v2.w * s;  ai[5] += v2.w * c - v2.z * s;
        ar[6] += v3.x * c + v3.y * s;  ai[6] += v3.y * c - v3.x * s;
        ar[7] += v3.z * c + v3.w * s;  ai[7] += v3.w * c - v3.z * s;
        if (kq == 0) {
            float2 v = zw[h][32];
            tr  += v.x * c + v.y * s;
            tiv += v.y * c - v.x * s;
        }
        float cn = c * sc - s * ss;
        s = s * sc + c * ss;
        c = cn;
    }

    float2* zrow = zm + (size_t)bc * 2112 + r * 33;
    #pragma unroll
    for (int j = 0; j < 8; ++j) zrow[kq * 8 + j] = make_float2(ar[j], ai[j]);
    if (kq == 0) zrow[32] = make_float2(tr, tiv);
}

// ---------------------------------------------------------------------------
// Kernel 2a: MLP layer 1 + exact GELU -> hbuf.
// ---------------------------------------------------------------------------
__global__ __launch_bounds__(256) void k_mlp1(const float* __restrict__ w1r_g,
                                              const float* __restrict__ w1i_g,
                                              const float* __restrict__ b1r_g,
                                              const float* __restrict__ b1i_g,
                                              const float2* __restrict__ zm,
                                              float2* __restrict__ hbuf) {
    __shared__ float w1r[4096], w1i[4096];
    __shared__ float b1r[64], b1i[64];
    __shared__ float zr[4][64], zi[4][64];
    const int chunk = blockIdx.x;
    const int nb    = blockIdx.y;
    const int b     = blockIdx.z;
    const int tid   = threadIdx.x;
    const int lane  = tid & 63;
    const int q     = tid >> 6;

    for (int t = tid; t < 4096; t += 256) {
        w1r[t] = w1r_g[nb * 4096 + t];
        w1i[t] = w1i_g[nb * 4096 + t];
    }
    if (tid < 64) { b1r[tid] = b1r_g[nb * 64 + tid]; b1i[tid] = b1i_g[nb * 64 + tid]; }
    __syncthreads();

    for (int g = 0; g < 16; ++g) {
        int pos = chunk * 64 + g * 4 + q;
        int r = pos / 33;
        int k = pos - r * 33;
        size_t idx = ((size_t)((b * 512 + nb * 64 + lane) * 64 + r)) * 33 + k;
        float2 z = zm[idx];
        zr[q][lane] = z.x; zi[q][lane] = z.y;
        __syncthreads();
        float yr = b1r[lane], yi = b1i[lane];
        #pragma unroll 16
        for (int i = 0; i < 64; ++i) {
            float arv = zr[q][i], aiv = zi[q][i];
            float wr = w1r[i * 64 + lane], wi = w1i[i * 64 + lane];
            yr += arv * wr - aiv * wi;
            yi += arv * wi + aiv * wr;
        }
        hbuf[idx] = make_float2(gelu_exact(yr), gelu_exact(yi));
        __syncthreads();
    }
}

// ---------------------------------------------------------------------------
// Kernel 2b: MLP layer 2 + softshrink; zm <- delta = softshrink(y2) - z
// ---------------------------------------------------------------------------
__global__ __launch_bounds__(256) void k_mlp2(const float* __restrict__ w2r_g,
                                              const float* __restrict__ w2i_g,
                                              const float* __restrict__ b2r_g,
                                              const float* __restrict__ b2i_g,
                                              const float2* __restrict__ hbuf,
                                              float2* __restrict__ zm) {
    __shared__ float w2r[4096], w2i[4096];
    __shared__ float b2r[64], b2i[64];
    __shared__ float hr[4][64], hi[4][64];
    const int chunk = blockIdx.x;
    const int nb    = blockIdx.y;
    const int b     = blockIdx.z;
    const int tid   = threadIdx.x;
    const int lane  = tid & 63;
    const int q     = tid >> 6;

    for (int t = tid; t < 4096; t += 256) {
        w2r[t] = w2r_g[nb * 4096 + t];
        w2i[t] = w2i_g[nb * 4096 + t];
    }
    if (tid < 64) { b2r[tid] = b2r_g[nb * 64 + tid]; b2i[tid] = b2i_g[nb * 64 + tid]; }
    __syncthreads();

    for (int g = 0; g < 16; ++g) {
        int pos = chunk * 64 + g * 4 + q;
        int r = pos / 33;
        int k = pos - r * 33;
        size_t idx = ((size_t)((b * 512 + nb * 64 + lane) * 64 + r)) * 33 + k;
        float2 h = hbuf[idx];
        hr[q][lane] = h.x; hi[q][lane] = h.y;
        __syncthreads();
        float yr = b2r[lane], yi = b2i[lane];
        #pragma unroll 16
        for (int i = 0; i < 64; ++i) {
            float arv = hr[q][i], aiv = hi[q][i];
            float wr = w2r[i * 64 + lane], wi = w2i[i * 64 + lane];
            yr += arv * wr - aiv * wi;
            yi += arv * wi + aiv * wr;
        }
        float2 z = zm[idx];
        zm[idx] = make_float2(softshrink01(yr) - z.x, softshrink01(yi) - z.y);
        __syncthreads();
    }
}

// ---------------------------------------------------------------------------
// Kernel 3: inverse per (b,c); writes yy_bf = bf16(x + D).
// ---------------------------------------------------------------------------
__global__ __launch_bounds__(256) void k_inv(const float2* __restrict__ zm,
                                             const float* __restrict__ x,
                                             unsigned short* __restrict__ yb) {
    __shared__ float2 dbuf[64][33];
    __shared__ float2 Tbuf[128][34];
    const int bc  = blockIdx.x;
    const int tid = threadIdx.x;

    for (int t = tid; t < 2112; t += 256)
        ((float2*)dbuf)[t] = zm[(size_t)bc * 2112 + t];
    __syncthreads();

    {
        const int h  = tid & 127;
        const int kg = tid >> 7;
        float sc, ss;
        sincosf((float)h * TWO_PI_OVER_128, &ss, &sc);
        float c = 1.0f, s = 0.0f;
        float ar[17], ai[17];
        #pragma unroll
        for (int j = 0; j < 17; ++j) { ar[j] = 0.f; ai[j] = 0.f; }
        for (int r = 0; r < 64; ++r) {
            #pragma unroll
            for (int j = 0; j < 17; ++j) {
                const int k = kg + 2 * j;
                if (k <= 32) {
                    float2 v = dbuf[r][k];
                    ar[j] += v.x * c - v.y * s;
                    ai[j] += v.y * c + v.x * s;
                }
            }
            float cn = c * sc - s * ss;
            s = s * sc + c * ss;
            c = cn;
        }
        #pragma unroll
        for (int j = 0; j < 17; ++j) {
            const int k = kg + 2 * j;
            if (k <= 32) Tbuf[h][k + 1] = make_float2(ar[j], ai[j]);
        }
    }
    __syncthreads();

    {
        const int w    = tid & 127;
        const int half = tid >> 7;
        float sc, ss;
        sincosf((float)w * TWO_PI_OVER_128, &ss, &sc);
        const size_t base = (size_t)bc * 16384;
        for (int hg = 0; hg < 8; ++hg) {
            const int h0 = half * 64 + hg * 8;
            float acc[8];
            #pragma unroll
            for (int i = 0; i < 8; ++i) acc[i] = 0.5f * Tbuf[h0 + i][1].x;
            float c = sc, s = ss;
            #pragma unroll
            for (int p = 0; p < 16; ++p) {
                float c1 = c * sc - s * ss;
                float s1 = s * sc + c * ss;
                #pragma unroll
                for (int i = 0; i < 8; ++i) {
                    float4 v = *(const float4*)&Tbuf[h0 + i][2 + 2 * p];
                    acc[i] += v.x * c - v.y * s + v.z * c1 - v.w * s1;
                }
                c = c1 * sc - s1 * ss;
                s = s1 * sc + c1 * ss;
            }
            #pragma unroll
            for (int i = 0; i < 8; ++i) {
                size_t idx = base + (size_t)(h0 + i) * 128 + w;
                yb[idx] = f2bf(x[idx] + acc[i] * 0.015625f);
            }
        }
    }
}

// ---------------------------------------------------------------------------
// Kernel 3b: transpose yy_bf[b][c][p] -> yy_t[b][p][c] (bf16), 64x64 tiles.
// ---------------------------------------------------------------------------
__global__ __launch_bounds__(256) void k_tr(const unsigned short* __restrict__ yb,
                                            unsigned short* __restrict__ yt) {
    __shared__ float ts[64][65];   // [p][c]
    const int p0 = blockIdx.x * 64;
    const int c0 = blockIdx.y * 64;
    const int b  = blockIdx.z;
    const int t  = threadIdx.x;
    const int lane = t & 63;

    const unsigned short* src = yb + (((size_t)(b * 512 + c0 + lane)) << 14) + p0;
    #pragma unroll
    for (int cc = 0; cc < 2; ++cc) {
        int ch = (t >> 6) * 2 + cc;          // p-chunk 0..7
        us8 v = *(const us8*)&src[ch * 8];
        #pragma unroll
        for (int j = 0; j < 8; ++j)
            ts[ch * 8 + j][lane] = __uint_as_float((unsigned)v[j] << 16);
    }
    __syncthreads();

    const int pr   = t >> 2;
    const int coff = (t & 3) * 16;
    us8 o0v, o1v;
    #pragma unroll
    for (int i = 0; i < 8; ++i) o0v[i] = f2bf(ts[pr][coff + i]);
    #pragma unroll
    for (int i = 0; i < 8; ++i) o1v[i] = f2bf(ts[pr][coff + 8 + i]);
    unsigned short* dst = yt + ((size_t)(b * 16384 + p0 + pr)) * 512 + c0 + coff;
    *(us8*)&dst[0] = o0v;
    *(us8*)&dst[8] = o1v;
}

// ---------------------------------------------------------------------------
// Kernel 3c: fw fp32 -> bf16 (row-major [o][c] unchanged).
// ---------------------------------------------------------------------------
__global__ __launch_bounds__(256) void k_prep(const float* __restrict__ fw,
                                              unsigned short* __restrict__ fb) {
    int i = (blockIdx.x * 256 + threadIdx.x) * 4;
    float4 v = *(const float4*)&fw[i];
    ushort4 o;
    o.x = f2bf(v.x); o.y = f2bf(v.y); o.z = f2bf(v.z); o.w = f2bf(v.w);
    *(ushort4*)&fb[i] = o;
}

// ---------------------------------------------------------------------------
// Kernel 4: MFMA conv GEMM. out[b][o][p] = x[b][o][p] + sum_c fb[o][c]*yt[b][p][c]
// 128x128 tile, BK=32, 4 waves (2x2 of 64x64), mfma_f32_16x16x32_bf16.
// LDS rows padded to 40 bf16 (80 B) -> b128 frag reads bank-uniform.
// Fragment maps (m89/m91/m120-verified): A: m=lane&15,k=quad*8+j;
// B: n=lane&15,k=quad*8+j; C/D: col(n)=lane&15, row(m)=quad*4+reg.
// ---------------------------------------------------------------------------
__global__ __launch_bounds__(256) void k_gemm(const unsigned short* __restrict__ fb,
                                              const unsigned short* __restrict__ yt,
                                              const float* __restrict__ x,
                                              float* __restrict__ out) {
    __shared__ short Al[128 * 40];
    __shared__ short Bl[128 * 40];
    const int p0  = blockIdx.x * 128;
    const int o0  = blockIdx.y * 128;
    const int b   = blockIdx.z;
    const int tid = threadIdx.x;
    const int lane = tid & 63;
    const int w    = tid >> 6;
    const int wo = (w >> 1) * 64, wp = (w & 1) * 64;

    f32x4 acc[4][4];
    #pragma unroll
    for (int i = 0; i < 4; ++i)
        #pragma unroll
        for (int j = 0; j < 4; ++j)
            acc[i][j] = (f32x4){0.f, 0.f, 0.f, 0.f};

    const int m15 = lane & 15, quad = lane >> 4;

    for (int kc = 0; kc < 512; kc += 32) {
        __syncthreads();
        #pragma unroll
        for (int cc = 0; cc < 2; ++cc) {
            int ch = tid + cc * 256;          // 0..511
            int r  = ch >> 2;                 // row 0..127
            int pt = ch & 3;                  // 8-bf16 part
            *(s8bf*)&Al[r * 40 + pt * 8] =
                *(const s8bf*)&fb[(size_t)(o0 + r) * 512 + kc + pt * 8];
            *(s8bf*)&Bl[r * 40 + pt * 8] =
                *(const s8bf*)&yt[((size_t)(b * 16384 + p0 + r)) * 512 + kc + pt * 8];
        }
        __syncthreads();

        s8bf af[4], bfr[4];
        #pragma unroll
        for (int i = 0; i < 4; ++i) {
            af[i]  = *(const s8bf*)&Al[(wo + i * 16 + m15) * 40 + quad * 8];
            bfr[i] = *(const s8bf*)&Bl[(wp + i * 16 + m15) * 40 + quad * 8];
        }
        #pragma unroll
        for (int mi = 0; mi < 4; ++mi)
            #pragma unroll
            for (int ni = 0; ni < 4; ++ni)
                acc[mi][ni] = __builtin_amdgcn_mfma_f32_16x16x32_bf16(
                    af[mi], bfr[ni], acc[mi][ni], 0, 0, 0);
    }

    #pragma unroll
    for (int mi = 0; mi < 4; ++mi) {
        #pragma unroll
        for (int ni = 0; ni < 4; ++ni) {
            #pragma unroll
            for (int r = 0; r < 4; ++r) {
                int o = o0 + wo + mi * 16 + quad * 4 + r;
                int p = p0 + wp + ni * 16 + m15;
                size_t idx = (((size_t)(b * 512 + o)) << 14) + p;
                out[idx] = x[idx] + acc[mi][ni][r];
            }
        }
    }
}

// ---------------------------------------------------------------------------
extern "C" void kernel_launch(void* const* d_in, const int* in_sizes, int n_in,
                              void* d_out, int out_size, void* d_ws, size_t ws_size,
                              hipStream_t stream) {
    const float* x   = (const float*)d_in[0];
    const float* w1r = (const float*)d_in[1];
    const float* w1i = (const float*)d_in[2];
    const float* b1r = (const float*)d_in[3];
    const float* b1i = (const float*)d_in[4];
    const float* w2r = (const float*)d_in[5];
    const float* w2i = (const float*)d_in[6];
    const float* b2r = (const float*)d_in[7];
    const float* b2i = (const float*)d_in[8];
    const float* fw  = (const float*)d_in[9];
    float* out = (float*)d_out;

    char* ws = (char*)d_ws;
    float2* zm          = (float2*)ws;                         // [0, 34.6MB)
    float2* hbuf        = (float2*)(ws + 34603008);            // dead after mlp2
    float2* zwg         = (float2*)(ws + 34603008);            // dead after fwd2
    unsigned short* ybf = (unsigned short*)(ws + 34603008);    // dead after k_tr
    unsigned short* yt  = (unsigned short*)(ws + 101711872);   // [101.7MB, 168.8MB)
    unsigned short* fb  = (unsigned short*)(ws + 34603008);    // written after k_tr

    k_fwd1<<<dim3(2048, 2), 256, 0, stream>>>(x, zwg);
    k_fwd2<<<2048, 256, 0, stream>>>(zwg, zm);
    k_mlp1<<<dim3(33, 8, 4), 256, 0, stream>>>(w1r, w1i, b1r, b1i, zm, hbuf);
    k_mlp2<<<dim3(33, 8, 4), 256, 0, stream>>>(w2r, w2i, b2r, b2i, hbuf, zm);
    k_inv<<<2048, 256, 0, stream>>>(zm, x, ybf);
    k_tr<<<dim3(256, 8, 4), 256, 0, stream>>>(ybf, yt);
    k_prep<<<256, 256, 0, stream>>>(fw, fb);
    k_gemm<<<dim3(128, 4, 4), 256, 0, stream>>>(fb, yt, x, out);
}